// Round 19
// baseline (362.791 us; speedup 1.0000x reference)
//
#include <hip/hip_runtime.h>
#include <hip/hip_bf16.h>
#include <stdint.h>

using bf16 = __hip_bfloat16;
typedef __attribute__((ext_vector_type(8))) short bf16x8;
typedef __attribute__((ext_vector_type(4))) float f32x4;
typedef __attribute__((ext_vector_type(2))) float f32x2;

#define NN 50000
#define NE 400000
#define NG 64
#define NHEADS 4
#define FIN 64
#define HID 96
#define CC3 64
#define NOUT 10

#define SCAN_BLOCK 256
#define NPART ((NN + SCAN_BLOCK - 1) / SCAN_BLOCK)   // 196 (<=256)
#define GB16 ((NN/16 + 3) / 4)                       // 782 gemm blocks (3125 row tiles)

__device__ __forceinline__ float b2f(bf16 h){ return __bfloat162float(h); }
__device__ __forceinline__ bf16 f2b(float f){ return __float2bfloat16(f); }

// ---------------- merged prologue: weight transposes + logit folding + zero-fills -----
#define NTJOBS 5
struct PrepJobs {
  const float* W[NTJOBS]; bf16* WT[NTJOBS]; int K[NTJOBS]; int Nc[NTJOBS];
  const float* LWm[3]; const float* Latt[3]; const float* Lbm[3];
  bf16* LWT[3]; int LK[3]; int LC[3]; int LncMain[3];
  float* lb;
  int* deg; float* psum; int* done;
};
__global__ __launch_bounds__(256) void prep_kernel(PrepJobs j){
  int bid = blockIdx.x;
  if (bid < 3){
    int l = bid;
    const float* Wm = j.LWm[l]; const float* att = j.Latt[l]; const float* bm = j.Lbm[l];
    bf16* WT = j.LWT[l];
    int K = j.LK[l], C = j.LC[l], ncMain = j.LncMain[l];
    for (int idx = threadIdx.x; idx < K*4; idx += 256){
      int k = idx >> 2, h = idx & 3;
      float a = 0.f;
      for (int c=0;c<C;++c) a += Wm[(size_t)k*(4*C) + h*C + c] * att[h*C + c];
      WT[(size_t)(ncMain+h)*K + k] = f2b(a);
    }
    for (int idx = threadIdx.x; idx < 12*K; idx += 256){
      int col = ncMain + 4 + idx / K, k = idx % K;
      WT[(size_t)col*K + k] = f2b(0.f);
    }
    if (threadIdx.x < 4){
      int h = threadIdx.x; float a = 0.f;
      for (int c=0;c<C;++c) a += bm[h*C + c] * att[h*C + c];
      j.lb[l*4 + h] = a;
    }
  } else if (bid < 3 + 256){
    int b = bid - 3;
    for (int t=0; t<NTJOBS; ++t){
      int K = j.K[t], Nc = j.Nc[t], total = K*Nc;
      for (int i = b*256 + threadIdx.x; i < total; i += 256*256){
        int k = i / Nc, n = i % Nc;
        j.WT[t][(size_t)n*K + k] = f2b(j.W[t][i]);
      }
    }
  } else if (bid < 3 + 256 + NPART){
    int i = (bid - 3 - 256)*256 + threadIdx.x;
    if (i < NN) j.deg[i] = 0;
  } else {
    for (int i = threadIdx.x; i < NG*CC3; i += 256) j.psum[i] = 0.f;
    if (threadIdx.x == 0) *j.done = 0;
  }
}

// ---------------- CSR build ----------------
__global__ void deg_kernel(const int* __restrict__ ei, int* __restrict__ deg){
  int e = blockIdx.x*256 + threadIdx.x;
  if (e < NE) atomicAdd(&deg[ei[NE + e]], 1);
}

// per-block sums; last-arriving block performs the top-level exclusive scan in place
__global__ __launch_bounds__(256) void scan_part_kernel(const int* __restrict__ deg,
    int* __restrict__ partials, int* __restrict__ done, int* __restrict__ off){
  __shared__ int ws[4];
  __shared__ int lastflag;
  __shared__ int buf[256];
  int i = blockIdx.x*SCAN_BLOCK + threadIdx.x;
  int v = (i < NN) ? deg[i] : 0;
  int lane = threadIdx.x & 63, w = threadIdx.x >> 6;
  int s = v;
  #pragma unroll
  for (int m=1;m<64;m<<=1) s += __shfl_xor(s,m);
  if (lane==0) ws[w]=s;
  __syncthreads();
  if (threadIdx.x==0){
    int tot = ws[0]+ws[1]+ws[2]+ws[3];
    atomicExch(&partials[blockIdx.x], tot);     // device-scope publish
    __threadfence();
    int old = atomicAdd(done, 1);
    lastflag = (old == NPART-1) ? 1 : 0;
  }
  __syncthreads();
  if (lastflag){
    int t = threadIdx.x;
    int pv = (t < NPART) ? atomicAdd(&partials[t], 0) : 0;   // device-scope read
    buf[t] = pv; __syncthreads();
    for (int st=1; st<256; st<<=1){
      int x = (t>=st) ? buf[t-st] : 0;
      __syncthreads();
      buf[t] += x;
      __syncthreads();
    }
    if (t < NPART) atomicExch(&partials[t], buf[t] - pv);    // exclusive
    if (t == 0) off[NN] = buf[255];
  }
}

__global__ __launch_bounds__(256) void scan_final_kernel(const int* __restrict__ deg,
    const int* __restrict__ partials, int* __restrict__ off, int* __restrict__ cursor){
  __shared__ int buf[256];
  int i = blockIdx.x*SCAN_BLOCK + threadIdx.x;
  int t = threadIdx.x;
  int v = (i<NN) ? deg[i] : 0;
  buf[t] = v; __syncthreads();
  for (int s=1;s<256;s<<=1){
    int x = (t>=s) ? buf[t-s] : 0;
    __syncthreads();
    buf[t] += x;
    __syncthreads();
  }
  int ex = partials[blockIdx.x] + buf[t] - v;
  if (i<NN){ off[i]=ex; cursor[i]=ex; }
}

__global__ void scatter_kernel(const int* __restrict__ ei, int* __restrict__ cursor,
                               int* __restrict__ csr_src){
  int e = blockIdx.x*256 + threadIdx.x;
  if (e < NE){
    int d = ei[NE + e];
    int slot = atomicAdd(&cursor[d], 1);
    csr_src[slot] = ei[e];
  }
}

// ---------------- MFMA GEMM, transposed output, LDS-staged coalesced stores ----------
template<int K, bool F32A>
__global__ __launch_bounds__(256) void gemm_mfma(const void* __restrict__ Ap,
    const bf16* __restrict__ WT, const float* __restrict__ biasMain,
    const float* __restrict__ lb4, uint8_t* __restrict__ outMain, int ncMain,
    float* __restrict__ EL, const float* __restrict__ biasSelf,
    bf16* __restrict__ outSelf, int ncSelf, int msgG, int totalU, int UPB)
{
  constexpr int KT = K/32;
  __shared__ unsigned int sbuf[4][16][16];   // 4 waves x 16 rows x 64B
  const int wave = threadIdx.x >> 6, lane = threadIdx.x & 63;
  const int tile = blockIdx.x*4 + wave;
  if (tile >= NN/16) return;
  const int lm = lane & 15, q = lane >> 4;
  const int nodeRow = tile*16 + lm;
  const int rdRow = lane >> 2, rdCol = lane & 3;
  const int outRow = tile*16 + rdRow;

  bf16x8 xfrag[KT];
  if (F32A){
    const float* Af = (const float*)Ap;
    #pragma unroll
    for (int kt=0; kt<KT; ++kt){
      float4 a0 = *(const float4*)(Af + (size_t)nodeRow*K + kt*32 + q*8);
      float4 a1 = *(const float4*)(Af + (size_t)nodeRow*K + kt*32 + q*8 + 4);
      bf16 tmp[8];
      tmp[0]=f2b(a0.x); tmp[1]=f2b(a0.y); tmp[2]=f2b(a0.z); tmp[3]=f2b(a0.w);
      tmp[4]=f2b(a1.x); tmp[5]=f2b(a1.y); tmp[6]=f2b(a1.z); tmp[7]=f2b(a1.w);
      xfrag[kt] = *(const bf16x8*)tmp;
    }
  } else {
    const bf16* A = (const bf16*)Ap;
    #pragma unroll
    for (int kt=0; kt<KT; ++kt)
      xfrag[kt] = *(const bf16x8*)(A + (size_t)nodeRow*K + kt*32 + q*8);
  }

  const int u0 = blockIdx.y*UPB, u1 = min(u0+UPB, totalU);
  for (int u=u0; u<u1; ++u){
    if (u < msgG){
      #pragma unroll
      for (int t=0;t<4;++t){
        int ct = u*4 + t;
        f32x4 acc = {};
        #pragma unroll
        for (int kt=0; kt<KT; ++kt){
          bf16x8 wfrag = *(const bf16x8*)(WT + (size_t)(ct*16+lm)*K + kt*32 + q*8);
          acc = __builtin_amdgcn_mfma_f32_16x16x32_bf16(wfrag, xfrag[kt], acc, 0,0,0);
        }
        int wc = ct*16 + q*4;
        float v0 = acc[0]+biasMain[wc],   v1 = acc[1]+biasMain[wc+1];
        float v2 = acc[2]+biasMain[wc+2], v3 = acc[3]+biasMain[wc+3];
        int pk = 0;
        pk = __builtin_amdgcn_cvt_pk_fp8_f32(v0, v1, pk, false);
        pk = __builtin_amdgcn_cvt_pk_fp8_f32(v2, v3, pk, true);
        sbuf[wave][lm][t*4 + q] = (unsigned int)pk;
      }
      __builtin_amdgcn_wave_barrier();
      uint4 v = *(uint4*)&sbuf[wave][rdRow][rdCol*4];
      *(uint4*)(outMain + (size_t)outRow*ncMain + u*64 + rdCol*16) = v;
      __builtin_amdgcn_wave_barrier();
    } else if (u == msgG){
      int ct = ncMain/16;
      f32x4 acc = {};
      #pragma unroll
      for (int kt=0; kt<KT; ++kt){
        bf16x8 wfrag = *(const bf16x8*)(WT + (size_t)(ct*16+lm)*K + kt*32 + q*8);
        acc = __builtin_amdgcn_mfma_f32_16x16x32_bf16(wfrag, xfrag[kt], acc, 0,0,0);
      }
      if (q == 0){
        float4 e;
        float l;
        l = acc[0]+lb4[0]; l = (l>=0.f)?l:0.2f*l; e.x = __expf(fminf(fmaxf(l,-60.f),60.f));
        l = acc[1]+lb4[1]; l = (l>=0.f)?l:0.2f*l; e.y = __expf(fminf(fmaxf(l,-60.f),60.f));
        l = acc[2]+lb4[2]; l = (l>=0.f)?l:0.2f*l; e.z = __expf(fminf(fmaxf(l,-60.f),60.f));
        l = acc[3]+lb4[3]; l = (l>=0.f)?l:0.2f*l; e.w = __expf(fminf(fmaxf(l,-60.f),60.f));
        *(float4*)(EL + 4*(size_t)nodeRow) = e;
      }
    } else {
      int sg = u - msgG - 1;
      #pragma unroll
      for (int t=0;t<2;++t){
        int ct = ncMain/16 + 1 + sg*2 + t;
        f32x4 acc = {};
        #pragma unroll
        for (int kt=0; kt<KT; ++kt){
          bf16x8 wfrag = *(const bf16x8*)(WT + (size_t)(ct*16+lm)*K + kt*32 + q*8);
          acc = __builtin_amdgcn_mfma_f32_16x16x32_bf16(wfrag, xfrag[kt], acc, 0,0,0);
        }
        int c = ct*16 + q*4 - ncMain - 16;
        bf16 st[4];
        st[0]=f2b(acc[0]+biasSelf[c]);   st[1]=f2b(acc[1]+biasSelf[c+1]);
        st[2]=f2b(acc[2]+biasSelf[c+2]); st[3]=f2b(acc[3]+biasSelf[c+3]);
        uint2 uu = *(uint2*)st;
        sbuf[wave][lm][t*8 + q*2]     = uu.x;
        sbuf[wave][lm][t*8 + q*2 + 1] = uu.y;
      }
      __builtin_amdgcn_wave_barrier();
      uint4 v = *(uint4*)&sbuf[wave][rdRow][rdCol*4];
      *(uint4*)(outSelf + (size_t)outRow*ncSelf + sg*32 + rdCol*8) = v;
      __builtin_amdgcn_wave_barrier();
    }
  }
}

// ---------------- conv aggregation: ONE node per wave (r14-proven), batches of 8 ------
// FP (layer 3, C==64): wave 0 pools the block's 4 consecutive nodes from LDS and
// flushes <=2 atomicAdds per channel into psum; H3 never materialized.
template<int C, bool FP>
__global__ __launch_bounds__(256) void conv_agg(const int* __restrict__ off,
    const int* __restrict__ csr_src, const float* __restrict__ EL,
    const uint8_t* __restrict__ M8, const bf16* __restrict__ Hself,
    bf16* __restrict__ Hout, const int* __restrict__ batch, float* __restrict__ psum)
{
  constexpr int R = 4*C;
  __shared__ float red[4][R];
  const int wave = threadIdx.x >> 6, lane = threadIdx.x & 63;
  const int n = blockIdx.x*4 + wave;
  const int e0 = off[n], e1 = off[n+1];

  const bool active = (8*lane) < R;
  const int hidx = min(3, (8*lane) / C);
  const int myoff = active ? lane*8 : 0;
  float acc[8] = {0,0,0,0,0,0,0,0};
  float dnl = 0.f;

  for (int base=e0; base<e1; base+=8){
    const int cnt8 = min(8, e1-base);
    int sreg = (lane < cnt8) ? csr_src[base+lane] : 0;
    int sv[8];
    #pragma unroll
    for (int j=0;j<8;++j) sv[j] = __shfl(sreg, j);     // v_readlane -> SGPR

    float wl[8]; uint2 u[8];
    #pragma unroll
    for (int j=0;j<8;++j){                             // 16 independent loads in flight
      wl[j] = EL[4*(size_t)sv[j] + hidx];
      u[j]  = *(const uint2*)(M8 + (size_t)sv[j]*R + myoff);
    }
    #pragma unroll
    for (int j=0;j<8;++j){
      float w = (j < cnt8) ? wl[j] : 0.f;
      dnl += w;
      f32x2 a0 = __builtin_amdgcn_cvt_pk_f32_fp8((int)u[j].x, false);
      f32x2 a1 = __builtin_amdgcn_cvt_pk_f32_fp8((int)u[j].x, true);
      f32x2 a2 = __builtin_amdgcn_cvt_pk_f32_fp8((int)u[j].y, false);
      f32x2 a3 = __builtin_amdgcn_cvt_pk_f32_fp8((int)u[j].y, true);
      acc[0] += a0.x*w;  acc[1] += a0.y*w;
      acc[2] += a1.x*w;  acc[3] += a1.y*w;
      acc[4] += a2.x*w;  acc[5] += a2.y*w;
      acc[6] += a3.x*w;  acc[7] += a3.y*w;
    }
  }

  float rd = 1.f/(dnl + 1e-16f);
  if (active){
    #pragma unroll
    for (int j=0;j<8;++j) red[wave][8*lane+j] = acc[j]*rd;
  }
  __syncthreads();

  if (!FP){
    for (int c=lane; c<C; c+=64){
      float v = 0.25f*(red[wave][c] + red[wave][C+c] + red[wave][2*C+c] + red[wave][3*C+c]);
      Hout[(size_t)n*C + c] = f2b(v + b2f(Hself[(size_t)n*C + c]));
    }
  } else {
    if (wave == 0){
      int c = lane;
      int nb0 = blockIdx.x*4;
      int curg = batch[nb0];
      float a = 0.f;
      #pragma unroll
      for (int i=0;i<4;++i){
        float v = 0.25f*(red[i][c] + red[i][C+c] + red[i][2*C+c] + red[i][3*C+c]);
        v += b2f(Hself[(size_t)(nb0+i)*C + c]);
        int g = batch[nb0+i];
        if (g != curg){ atomicAdd(&psum[curg*C + c], a); a = 0.f; curg = g; }
        a += v;
      }
      atomicAdd(&psum[curg*C + c], a);
    }
  }
}

// ---------------- classifier + log_softmax (f32 weights & output) ----------------
__global__ __launch_bounds__(64) void fc_kernel(const float* __restrict__ psum,
    const int* __restrict__ batch, const float* __restrict__ Wfc,
    const float* __restrict__ bfc, float* __restrict__ out){
  int g = blockIdx.x, t = threadIdx.x;
  __shared__ int sb[2];
  if (t < 2){
    int target = g + t;
    int lo=0, hi=NN;
    while (lo<hi){ int mid=(lo+hi)>>1; if (batch[mid]<target) lo=mid+1; else hi=mid; }
    sb[t]=lo;
  }
  __syncthreads();
  float cnt = (float)(sb[1]-sb[0]);
  __shared__ float p[CC3];
  __shared__ float lg[NOUT];
  p[t] = psum[g*CC3 + t] / fmaxf(cnt, 1.0f);
  __syncthreads();
  if (t < NOUT){
    float a = bfc[t];
    for (int c=0;c<CC3;++c) a += p[c]*Wfc[c*NOUT + t];
    lg[t] = a;
  }
  __syncthreads();
  if (t < NOUT){
    float m = -INFINITY;
    #pragma unroll
    for (int i=0;i<NOUT;++i) m = fmaxf(m, lg[i]);
    float s = 0.f;
    #pragma unroll
    for (int i=0;i<NOUT;++i) s += __expf(lg[i]-m);
    out[g*NOUT + t] = lg[t] - m - __logf(s);
  }
}

extern "C" void kernel_launch(void* const* d_in, const int* in_sizes, int n_in,
                              void* d_out, int out_size, void* d_ws, size_t ws_size,
                              hipStream_t stream) {
  const float* xf    = (const float*)d_in[0];
  const int*   ei    = (const int*)d_in[1];
  const int*   batch = (const int*)d_in[2];
  const float* pWm1  = (const float*)d_in[3];
  const float* pbm1  = (const float*)d_in[4];
  const float* patt1 = (const float*)d_in[5];
  const float* pWs1  = (const float*)d_in[6];
  const float* pbs1  = (const float*)d_in[7];
  const float* pWm2  = (const float*)d_in[8];
  const float* pbm2  = (const float*)d_in[9];
  const float* patt2 = (const float*)d_in[10];
  const float* pWm3  = (const float*)d_in[11];
  const float* pbm3  = (const float*)d_in[12];
  const float* patt3 = (const float*)d_in[13];
  const float* pWs3  = (const float*)d_in[14];
  const float* pbs3  = (const float*)d_in[15];
  const float* pWfc  = (const float*)d_in[16];
  const float* pbfc  = (const float*)d_in[17];

  // ---- workspace layout, lifetime-aliased ----
  char* p = (char*)d_ws;
  auto alloc = [&](size_t bytes)->char*{ char* q = p; p += (bytes + 255) & ~(size_t)255; return q; };
  int*     deg     = (int*)  alloc(NN*sizeof(int));
  int*     off     = (int*)  alloc((NN+1)*sizeof(int));
  int*     cursor  = (int*)  alloc(NN*sizeof(int));
  int*     csr_src = (int*)  alloc(NE*sizeof(int));
  int*     partials= (int*)  alloc(NPART*sizeof(int));
  int*     done    = (int*)  alloc(sizeof(int));
  float*   EL      = (float*)alloc((size_t)NN*4*sizeof(float));  // 800 KB
  uint8_t* Mb8     = (uint8_t*)alloc((size_t)NN*384);            // 19.2 MB fp8, aligned rows
  bf16*    H1b     = (bf16*) alloc((size_t)NN*96*sizeof(bf16));  // 9.6 MB; H3 aliases this
  bf16*    H2b     = (bf16*) alloc((size_t)NN*96*sizeof(bf16));  // 9.6 MB
  float*   psum    = (float*)alloc((size_t)NG*CC3*sizeof(float));
  // concatenated WT: [main | 16-col logit tile | self]
  bf16*  WT1cat = (bf16*)alloc((size_t)496*FIN*sizeof(bf16));   // 384 | 16 | 96
  bf16*  WT2cat = (bf16*)alloc((size_t)400*HID*sizeof(bf16));   // 384 | 16
  bf16*  WT3cat = (bf16*)alloc((size_t)336*HID*sizeof(bf16));   // 256 | 16 | 64
  float* lb     = (float*)alloc(12*sizeof(float));
  bf16*  H3b = H1b;   // layer-3 self buffer (H1 dead after layer-2 agg)

  // ---- merged prologue (transposes + logit folding + deg/psum/done zeroing) ----
  PrepJobs pj;
  pj.W[0]=pWm1; pj.WT[0]=WT1cat;                 pj.K[0]=FIN; pj.Nc[0]=384;
  pj.W[1]=pWs1; pj.WT[1]=WT1cat+(size_t)400*FIN; pj.K[1]=FIN; pj.Nc[1]=96;
  pj.W[2]=pWm2; pj.WT[2]=WT2cat;                 pj.K[2]=HID; pj.Nc[2]=384;
  pj.W[3]=pWm3; pj.WT[3]=WT3cat;                 pj.K[3]=HID; pj.Nc[3]=256;
  pj.W[4]=pWs3; pj.WT[4]=WT3cat+(size_t)272*HID; pj.K[4]=HID; pj.Nc[4]=64;
  pj.LWm[0]=pWm1; pj.Latt[0]=patt1; pj.Lbm[0]=pbm1; pj.LWT[0]=WT1cat; pj.LK[0]=FIN; pj.LC[0]=96; pj.LncMain[0]=384;
  pj.LWm[1]=pWm2; pj.Latt[1]=patt2; pj.Lbm[1]=pbm2; pj.LWT[1]=WT2cat; pj.LK[1]=HID; pj.LC[1]=96; pj.LncMain[1]=384;
  pj.LWm[2]=pWm3; pj.Latt[2]=patt3; pj.Lbm[2]=pbm3; pj.LWT[2]=WT3cat; pj.LK[2]=HID; pj.LC[2]=64; pj.LncMain[2]=256;
  pj.lb = lb; pj.deg = deg; pj.psum = psum; pj.done = done;
  prep_kernel<<<3+256+NPART+1, 256, 0, stream>>>(pj);

  // ---- CSR build (deg -> fused part+top scan -> final scan -> scatter) ----
  deg_kernel<<<(NE+255)/256, 256, 0, stream>>>(ei, deg);
  scan_part_kernel<<<NPART, 256, 0, stream>>>(deg, partials, done, off);
  scan_final_kernel<<<NPART, 256, 0, stream>>>(deg, partials, off, cursor);
  scatter_kernel<<<(NE+255)/256, 256, 0, stream>>>(ei, cursor, csr_src);

  const int AB = NN/4;                    // 12500 agg blocks (4 waves, 1 node each)

  // ---- layer 1: FIN=64 -> HID=96; units = 6 msgG + 1 logit + 3 selfG = 10, UPB=5 -> y=2
  gemm_mfma<64,true><<<dim3(GB16,2), 256, 0, stream>>>(xf, WT1cat, pbm1, lb,
                                                       Mb8, 384, EL, pbs1, H1b, 96,
                                                       6, 10, 5);
  conv_agg<96,false><<<AB, 256, 0, stream>>>(off, csr_src, EL, Mb8, H1b, H1b,
                                             batch, psum);
  // ---- layer 2: HID -> HID; units = 6 + 1 = 7, UPB=4 -> y=2 (identity self) ----
  gemm_mfma<96,false><<<dim3(GB16,2), 256, 0, stream>>>(H1b, WT2cat, pbm2, lb+4,
                                                        Mb8, 384, EL, pbm2, nullptr, 0,
                                                        6, 7, 4);
  conv_agg<96,false><<<AB, 256, 0, stream>>>(off, csr_src, EL, Mb8, H1b, H2b,
                                             batch, psum);
  // ---- layer 3: HID -> CC3=64; units = 4 + 1 + 2 = 7, UPB=4 -> y=2; pool fused ----
  gemm_mfma<96,false><<<dim3(GB16,2), 256, 0, stream>>>(H2b, WT3cat, pbm3, lb+8,
                                                        Mb8, 256, EL, pbs3, H3b, 64,
                                                        4, 7, 4);
  conv_agg<64,true><<<AB, 256, 0, stream>>>(off, csr_src, EL, Mb8, H3b, nullptr,
                                            batch, psum);

  // ---- classifier ----
  fc_kernel<<<NG, 64, 0, stream>>>(psum, batch, pWfc, pbfc, (float*)d_out);
}

// Round 20
// 353.675 us; speedup vs baseline: 1.0258x; 1.0258x over previous
//
#include <hip/hip_runtime.h>
#include <hip/hip_bf16.h>
#include <stdint.h>

using bf16 = __hip_bfloat16;
typedef __attribute__((ext_vector_type(8))) short bf16x8;
typedef __attribute__((ext_vector_type(4))) float f32x4;
typedef __attribute__((ext_vector_type(2))) float f32x2;

#define NN 50000
#define NE 400000
#define NG 64
#define NHEADS 4
#define FIN 64
#define HID 96
#define CC3 64
#define NOUT 10

#define SCAN_BLOCK 256
#define NPART ((NN + SCAN_BLOCK - 1) / SCAN_BLOCK)   // 196 (<=256)
#define GB16 ((NN/16 + 3) / 4)                       // 782 gemm blocks (3125 row tiles)

__device__ __forceinline__ float b2f(bf16 h){ return __bfloat162float(h); }
__device__ __forceinline__ bf16 f2b(float f){ return __float2bfloat16(f); }

// ---------------- merged prologue: weight transposes + logit folding + zero-fills -----
#define NTJOBS 5
struct PrepJobs {
  const float* W[NTJOBS]; bf16* WT[NTJOBS]; int K[NTJOBS]; int Nc[NTJOBS];
  const float* LWm[3]; const float* Latt[3]; const float* Lbm[3];
  bf16* LWT[3]; int LK[3]; int LC[3]; int LncMain[3];
  float* lb;
  int* deg; float* psum; int* done;
};
__global__ __launch_bounds__(256) void prep_kernel(PrepJobs j){
  int bid = blockIdx.x;
  if (bid < 3){
    int l = bid;
    const float* Wm = j.LWm[l]; const float* att = j.Latt[l]; const float* bm = j.Lbm[l];
    bf16* WT = j.LWT[l];
    int K = j.LK[l], C = j.LC[l], ncMain = j.LncMain[l];
    for (int idx = threadIdx.x; idx < K*4; idx += 256){
      int k = idx >> 2, h = idx & 3;
      float a = 0.f;
      for (int c=0;c<C;++c) a += Wm[(size_t)k*(4*C) + h*C + c] * att[h*C + c];
      WT[(size_t)(ncMain+h)*K + k] = f2b(a);
    }
    for (int idx = threadIdx.x; idx < 12*K; idx += 256){
      int col = ncMain + 4 + idx / K, k = idx % K;
      WT[(size_t)col*K + k] = f2b(0.f);
    }
    if (threadIdx.x < 4){
      int h = threadIdx.x; float a = 0.f;
      for (int c=0;c<C;++c) a += bm[h*C + c] * att[h*C + c];
      j.lb[l*4 + h] = a;
    }
  } else if (bid < 3 + 256){
    int b = bid - 3;
    for (int t=0; t<NTJOBS; ++t){
      int K = j.K[t], Nc = j.Nc[t], total = K*Nc;
      for (int i = b*256 + threadIdx.x; i < total; i += 256*256){
        int k = i / Nc, n = i % Nc;
        j.WT[t][(size_t)n*K + k] = f2b(j.W[t][i]);
      }
    }
  } else if (bid < 3 + 256 + NPART){
    int i = (bid - 3 - 256)*256 + threadIdx.x;
    if (i < NN) j.deg[i] = 0;
  } else {
    for (int i = threadIdx.x; i < NG*CC3; i += 256) j.psum[i] = 0.f;
    if (threadIdx.x == 0) *j.done = 0;
  }
}

// ---------------- CSR build ----------------
__global__ void deg_kernel(const int* __restrict__ ei, int* __restrict__ deg){
  int e = blockIdx.x*256 + threadIdx.x;
  if (e < NE) atomicAdd(&deg[ei[NE + e]], 1);
}

// per-block sums; last-arriving block performs the top-level exclusive scan in place
__global__ __launch_bounds__(256) void scan_part_kernel(const int* __restrict__ deg,
    int* __restrict__ partials, int* __restrict__ done, int* __restrict__ off){
  __shared__ int ws[4];
  __shared__ int lastflag;
  __shared__ int buf[256];
  int i = blockIdx.x*SCAN_BLOCK + threadIdx.x;
  int v = (i < NN) ? deg[i] : 0;
  int lane = threadIdx.x & 63, w = threadIdx.x >> 6;
  int s = v;
  #pragma unroll
  for (int m=1;m<64;m<<=1) s += __shfl_xor(s,m);
  if (lane==0) ws[w]=s;
  __syncthreads();
  if (threadIdx.x==0){
    int tot = ws[0]+ws[1]+ws[2]+ws[3];
    atomicExch(&partials[blockIdx.x], tot);     // device-scope publish
    __threadfence();
    int old = atomicAdd(done, 1);
    lastflag = (old == NPART-1) ? 1 : 0;
  }
  __syncthreads();
  if (lastflag){
    int t = threadIdx.x;
    int pv = (t < NPART) ? atomicAdd(&partials[t], 0) : 0;   // device-scope read
    buf[t] = pv; __syncthreads();
    for (int st=1; st<256; st<<=1){
      int x = (t>=st) ? buf[t-st] : 0;
      __syncthreads();
      buf[t] += x;
      __syncthreads();
    }
    if (t < NPART) atomicExch(&partials[t], buf[t] - pv);    // exclusive
    if (t == 0) off[NN] = buf[255];
  }
}

__global__ __launch_bounds__(256) void scan_final_kernel(const int* __restrict__ deg,
    const int* __restrict__ partials, int* __restrict__ off, int* __restrict__ cursor){
  __shared__ int buf[256];
  int i = blockIdx.x*SCAN_BLOCK + threadIdx.x;
  int t = threadIdx.x;
  int v = (i<NN) ? deg[i] : 0;
  buf[t] = v; __syncthreads();
  for (int s=1;s<256;s<<=1){
    int x = (t>=s) ? buf[t-s] : 0;
    __syncthreads();
    buf[t] += x;
    __syncthreads();
  }
  int ex = partials[blockIdx.x] + buf[t] - v;
  if (i<NN){ off[i]=ex; cursor[i]=ex; }
}

__global__ void scatter_kernel(const int* __restrict__ ei, int* __restrict__ cursor,
                               int* __restrict__ csr_src){
  int e = blockIdx.x*256 + threadIdx.x;
  if (e < NE){
    int d = ei[NE + e];
    int slot = atomicAdd(&cursor[d], 1);
    csr_src[slot] = ei[e];
  }
}

// ---------------- MFMA GEMM, transposed output, LDS-staged coalesced stores ----------
template<int K, bool F32A>
__global__ __launch_bounds__(256) void gemm_mfma(const void* __restrict__ Ap,
    const bf16* __restrict__ WT, const float* __restrict__ biasMain,
    const float* __restrict__ lb4, uint8_t* __restrict__ outMain, int ncMain,
    float* __restrict__ EL, const float* __restrict__ biasSelf,
    bf16* __restrict__ outSelf, int ncSelf, int msgG, int totalU, int UPB)
{
  constexpr int KT = K/32;
  __shared__ unsigned int sbuf[4][16][16];   // 4 waves x 16 rows x 64B
  const int wave = threadIdx.x >> 6, lane = threadIdx.x & 63;
  const int tile = blockIdx.x*4 + wave;
  if (tile >= NN/16) return;
  const int lm = lane & 15, q = lane >> 4;
  const int nodeRow = tile*16 + lm;
  const int rdRow = lane >> 2, rdCol = lane & 3;
  const int outRow = tile*16 + rdRow;

  bf16x8 xfrag[KT];
  if (F32A){
    const float* Af = (const float*)Ap;
    #pragma unroll
    for (int kt=0; kt<KT; ++kt){
      float4 a0 = *(const float4*)(Af + (size_t)nodeRow*K + kt*32 + q*8);
      float4 a1 = *(const float4*)(Af + (size_t)nodeRow*K + kt*32 + q*8 + 4);
      bf16 tmp[8];
      tmp[0]=f2b(a0.x); tmp[1]=f2b(a0.y); tmp[2]=f2b(a0.z); tmp[3]=f2b(a0.w);
      tmp[4]=f2b(a1.x); tmp[5]=f2b(a1.y); tmp[6]=f2b(a1.z); tmp[7]=f2b(a1.w);
      xfrag[kt] = *(const bf16x8*)tmp;
    }
  } else {
    const bf16* A = (const bf16*)Ap;
    #pragma unroll
    for (int kt=0; kt<KT; ++kt)
      xfrag[kt] = *(const bf16x8*)(A + (size_t)nodeRow*K + kt*32 + q*8);
  }

  const int u0 = blockIdx.y*UPB, u1 = min(u0+UPB, totalU);
  for (int u=u0; u<u1; ++u){
    if (u < msgG){
      #pragma unroll
      for (int t=0;t<4;++t){
        int ct = u*4 + t;
        f32x4 acc = {};
        #pragma unroll
        for (int kt=0; kt<KT; ++kt){
          bf16x8 wfrag = *(const bf16x8*)(WT + (size_t)(ct*16+lm)*K + kt*32 + q*8);
          acc = __builtin_amdgcn_mfma_f32_16x16x32_bf16(wfrag, xfrag[kt], acc, 0,0,0);
        }
        int wc = ct*16 + q*4;
        float v0 = acc[0]+biasMain[wc],   v1 = acc[1]+biasMain[wc+1];
        float v2 = acc[2]+biasMain[wc+2], v3 = acc[3]+biasMain[wc+3];
        int pk = 0;
        pk = __builtin_amdgcn_cvt_pk_fp8_f32(v0, v1, pk, false);
        pk = __builtin_amdgcn_cvt_pk_fp8_f32(v2, v3, pk, true);
        sbuf[wave][lm][t*4 + q] = (unsigned int)pk;
      }
      __builtin_amdgcn_wave_barrier();
      uint4 v = *(uint4*)&sbuf[wave][rdRow][rdCol*4];
      *(uint4*)(outMain + (size_t)outRow*ncMain + u*64 + rdCol*16) = v;
      __builtin_amdgcn_wave_barrier();
    } else if (u == msgG){
      int ct = ncMain/16;
      f32x4 acc = {};
      #pragma unroll
      for (int kt=0; kt<KT; ++kt){
        bf16x8 wfrag = *(const bf16x8*)(WT + (size_t)(ct*16+lm)*K + kt*32 + q*8);
        acc = __builtin_amdgcn_mfma_f32_16x16x32_bf16(wfrag, xfrag[kt], acc, 0,0,0);
      }
      if (q == 0){
        float4 e;
        float l;
        l = acc[0]+lb4[0]; l = (l>=0.f)?l:0.2f*l; e.x = __expf(fminf(fmaxf(l,-60.f),60.f));
        l = acc[1]+lb4[1]; l = (l>=0.f)?l:0.2f*l; e.y = __expf(fminf(fmaxf(l,-60.f),60.f));
        l = acc[2]+lb4[2]; l = (l>=0.f)?l:0.2f*l; e.z = __expf(fminf(fmaxf(l,-60.f),60.f));
        l = acc[3]+lb4[3]; l = (l>=0.f)?l:0.2f*l; e.w = __expf(fminf(fmaxf(l,-60.f),60.f));
        *(float4*)(EL + 4*(size_t)nodeRow) = e;
      }
    } else {
      int sg = u - msgG - 1;
      #pragma unroll
      for (int t=0;t<2;++t){
        int ct = ncMain/16 + 1 + sg*2 + t;
        f32x4 acc = {};
        #pragma unroll
        for (int kt=0; kt<KT; ++kt){
          bf16x8 wfrag = *(const bf16x8*)(WT + (size_t)(ct*16+lm)*K + kt*32 + q*8);
          acc = __builtin_amdgcn_mfma_f32_16x16x32_bf16(wfrag, xfrag[kt], acc, 0,0,0);
        }
        int c = ct*16 + q*4 - ncMain - 16;
        bf16 st[4];
        st[0]=f2b(acc[0]+biasSelf[c]);   st[1]=f2b(acc[1]+biasSelf[c+1]);
        st[2]=f2b(acc[2]+biasSelf[c+2]); st[3]=f2b(acc[3]+biasSelf[c+3]);
        uint2 uu = *(uint2*)st;
        sbuf[wave][lm][t*8 + q*2]     = uu.x;
        sbuf[wave][lm][t*8 + q*2 + 1] = uu.y;
      }
      __builtin_amdgcn_wave_barrier();
      uint4 v = *(uint4*)&sbuf[wave][rdRow][rdCol*4];
      *(uint4*)(outSelf + (size_t)outRow*ncSelf + sg*32 + rdCol*8) = v;
      __builtin_amdgcn_wave_barrier();
    }
  }
}

// ---------------- conv aggregation: ONE node per wave (r14-proven), batches of 8 ------
// FP (layer 3, C==64): wave 0 pools the block's 4 consecutive nodes from LDS and
// flushes <=2 atomicAdds per channel into psum; H3 never materialized.
template<int C, bool FP>
__global__ __launch_bounds__(256) void conv_agg(const int* __restrict__ off,
    const int* __restrict__ csr_src, const float* __restrict__ EL,
    const uint8_t* __restrict__ M8, const bf16* __restrict__ Hself,
    bf16* __restrict__ Hout, const int* __restrict__ batch, float* __restrict__ psum)
{
  constexpr int R = 4*C;
  __shared__ float red[4][R];
  const int wave = threadIdx.x >> 6, lane = threadIdx.x & 63;
  const int n = blockIdx.x*4 + wave;
  const int e0 = off[n], e1 = off[n+1];

  const bool active = (8*lane) < R;
  const int hidx = min(3, (8*lane) / C);
  const int myoff = active ? lane*8 : 0;
  float acc[8] = {0,0,0,0,0,0,0,0};
  float dnl = 0.f;

  for (int base=e0; base<e1; base+=8){
    const int cnt8 = min(8, e1-base);
    int sreg = (lane < cnt8) ? csr_src[base+lane] : 0;
    int sv[8];
    #pragma unroll
    for (int j=0;j<8;++j) sv[j] = __shfl(sreg, j);     // v_readlane -> SGPR

    float wl[8]; uint2 u[8];
    #pragma unroll
    for (int j=0;j<8;++j){                             // 16 independent loads in flight
      wl[j] = EL[4*(size_t)sv[j] + hidx];
      u[j]  = *(const uint2*)(M8 + (size_t)sv[j]*R + myoff);
    }
    #pragma unroll
    for (int j=0;j<8;++j){
      float w = (j < cnt8) ? wl[j] : 0.f;
      dnl += w;
      f32x2 a0 = __builtin_amdgcn_cvt_pk_f32_fp8((int)u[j].x, false);
      f32x2 a1 = __builtin_amdgcn_cvt_pk_f32_fp8((int)u[j].x, true);
      f32x2 a2 = __builtin_amdgcn_cvt_pk_f32_fp8((int)u[j].y, false);
      f32x2 a3 = __builtin_amdgcn_cvt_pk_f32_fp8((int)u[j].y, true);
      acc[0] += a0.x*w;  acc[1] += a0.y*w;
      acc[2] += a1.x*w;  acc[3] += a1.y*w;
      acc[4] += a2.x*w;  acc[5] += a2.y*w;
      acc[6] += a3.x*w;  acc[7] += a3.y*w;
    }
  }

  float rd = 1.f/(dnl + 1e-16f);
  if (active){
    #pragma unroll
    for (int j=0;j<8;++j) red[wave][8*lane+j] = acc[j]*rd;
  }
  __syncthreads();

  if (!FP){
    for (int c=lane; c<C; c+=64){
      float v = 0.25f*(red[wave][c] + red[wave][C+c] + red[wave][2*C+c] + red[wave][3*C+c]);
      Hout[(size_t)n*C + c] = f2b(v + b2f(Hself[(size_t)n*C + c]));
    }
  } else {
    if (wave == 0){
      int c = lane;
      int nb0 = blockIdx.x*4;
      int curg = batch[nb0];
      float a = 0.f;
      #pragma unroll
      for (int i=0;i<4;++i){
        float v = 0.25f*(red[i][c] + red[i][C+c] + red[i][2*C+c] + red[i][3*C+c]);
        v += b2f(Hself[(size_t)(nb0+i)*C + c]);
        int g = batch[nb0+i];
        if (g != curg){ atomicAdd(&psum[curg*C + c], a); a = 0.f; curg = g; }
        a += v;
      }
      atomicAdd(&psum[curg*C + c], a);
    }
  }
}

// ---------------- classifier + log_softmax (f32 weights & output) ----------------
__global__ __launch_bounds__(64) void fc_kernel(const float* __restrict__ psum,
    const int* __restrict__ batch, const float* __restrict__ Wfc,
    const float* __restrict__ bfc, float* __restrict__ out){
  int g = blockIdx.x, t = threadIdx.x;
  __shared__ int sb[2];
  if (t < 2){
    int target = g + t;
    int lo=0, hi=NN;
    while (lo<hi){ int mid=(lo+hi)>>1; if (batch[mid]<target) lo=mid+1; else hi=mid; }
    sb[t]=lo;
  }
  __syncthreads();
  float cnt = (float)(sb[1]-sb[0]);
  __shared__ float p[CC3];
  __shared__ float lg[NOUT];
  p[t] = psum[g*CC3 + t] / fmaxf(cnt, 1.0f);
  __syncthreads();
  if (t < NOUT){
    float a = bfc[t];
    for (int c=0;c<CC3;++c) a += p[c]*Wfc[c*NOUT + t];
    lg[t] = a;
  }
  __syncthreads();
  if (t < NOUT){
    float m = -INFINITY;
    #pragma unroll
    for (int i=0;i<NOUT;++i) m = fmaxf(m, lg[i]);
    float s = 0.f;
    #pragma unroll
    for (int i=0;i<NOUT;++i) s += __expf(lg[i]-m);
    out[g*NOUT + t] = lg[t] - m - __logf(s);
  }
}

extern "C" void kernel_launch(void* const* d_in, const int* in_sizes, int n_in,
                              void* d_out, int out_size, void* d_ws, size_t ws_size,
                              hipStream_t stream) {
  const float* xf    = (const float*)d_in[0];
  const int*   ei    = (const int*)d_in[1];
  const int*   batch = (const int*)d_in[2];
  const float* pWm1  = (const float*)d_in[3];
  const float* pbm1  = (const float*)d_in[4];
  const float* patt1 = (const float*)d_in[5];
  const float* pWs1  = (const float*)d_in[6];
  const float* pbs1  = (const float*)d_in[7];
  const float* pWm2  = (const float*)d_in[8];
  const float* pbm2  = (const float*)d_in[9];
  const float* patt2 = (const float*)d_in[10];
  const float* pWm3  = (const float*)d_in[11];
  const float* pbm3  = (const float*)d_in[12];
  const float* patt3 = (const float*)d_in[13];
  const float* pWs3  = (const float*)d_in[14];
  const float* pbs3  = (const float*)d_in[15];
  const float* pWfc  = (const float*)d_in[16];
  const float* pbfc  = (const float*)d_in[17];

  // ---- workspace layout, lifetime-aliased ----
  char* p = (char*)d_ws;
  auto alloc = [&](size_t bytes)->char*{ char* q = p; p += (bytes + 255) & ~(size_t)255; return q; };
  int*     deg     = (int*)  alloc(NN*sizeof(int));
  int*     off     = (int*)  alloc((NN+1)*sizeof(int));
  int*     cursor  = (int*)  alloc(NN*sizeof(int));
  int*     csr_src = (int*)  alloc(NE*sizeof(int));
  int*     partials= (int*)  alloc(NPART*sizeof(int));
  int*     done    = (int*)  alloc(sizeof(int));
  float*   EL      = (float*)alloc((size_t)NN*4*sizeof(float));  // 800 KB
  uint8_t* Mb8     = (uint8_t*)alloc((size_t)NN*384);            // 19.2 MB fp8, aligned rows
  bf16*    H1b     = (bf16*) alloc((size_t)NN*96*sizeof(bf16));  // 9.6 MB; H3 aliases this
  bf16*    H2b     = (bf16*) alloc((size_t)NN*96*sizeof(bf16));  // 9.6 MB
  float*   psum    = (float*)alloc((size_t)NG*CC3*sizeof(float));
  // concatenated WT: [main | 16-col logit tile | self]
  bf16*  WT1cat = (bf16*)alloc((size_t)496*FIN*sizeof(bf16));   // 384 | 16 | 96
  bf16*  WT2cat = (bf16*)alloc((size_t)400*HID*sizeof(bf16));   // 384 | 16
  bf16*  WT3cat = (bf16*)alloc((size_t)336*HID*sizeof(bf16));   // 256 | 16 | 64
  float* lb     = (float*)alloc(12*sizeof(float));
  bf16*  H3b = H1b;   // layer-3 self buffer (H1 dead after layer-2 agg)

  // ---- merged prologue (transposes + logit folding + deg/psum/done zeroing) ----
  PrepJobs pj;
  pj.W[0]=pWm1; pj.WT[0]=WT1cat;                 pj.K[0]=FIN; pj.Nc[0]=384;
  pj.W[1]=pWs1; pj.WT[1]=WT1cat+(size_t)400*FIN; pj.K[1]=FIN; pj.Nc[1]=96;
  pj.W[2]=pWm2; pj.WT[2]=WT2cat;                 pj.K[2]=HID; pj.Nc[2]=384;
  pj.W[3]=pWm3; pj.WT[3]=WT3cat;                 pj.K[3]=HID; pj.Nc[3]=256;
  pj.W[4]=pWs3; pj.WT[4]=WT3cat+(size_t)272*HID; pj.K[4]=HID; pj.Nc[4]=64;
  pj.LWm[0]=pWm1; pj.Latt[0]=patt1; pj.Lbm[0]=pbm1; pj.LWT[0]=WT1cat; pj.LK[0]=FIN; pj.LC[0]=96; pj.LncMain[0]=384;
  pj.LWm[1]=pWm2; pj.Latt[1]=patt2; pj.Lbm[1]=pbm2; pj.LWT[1]=WT2cat; pj.LK[1]=HID; pj.LC[1]=96; pj.LncMain[1]=384;
  pj.LWm[2]=pWm3; pj.Latt[2]=patt3; pj.Lbm[2]=pbm3; pj.LWT[2]=WT3cat; pj.LK[2]=HID; pj.LC[2]=64; pj.LncMain[2]=256;
  pj.lb = lb; pj.deg = deg; pj.psum = psum; pj.done = done;
  prep_kernel<<<3+256+NPART+1, 256, 0, stream>>>(pj);

  // ---- CSR build (deg -> fused part+top scan -> final scan -> scatter) ----
  deg_kernel<<<(NE+255)/256, 256, 0, stream>>>(ei, deg);
  scan_part_kernel<<<NPART, 256, 0, stream>>>(deg, partials, done, off);
  scan_final_kernel<<<NPART, 256, 0, stream>>>(deg, partials, off, cursor);
  scatter_kernel<<<(NE+255)/256, 256, 0, stream>>>(ei, cursor, csr_src);

  const int AB = NN/4;                    // 12500 agg blocks (4 waves, 1 node each)

  // ---- layer 1: FIN=64 -> HID=96; units = 6 msgG + 1 logit + 3 selfG = 10, UPB=3 -> y=4
  gemm_mfma<64,true><<<dim3(GB16,4), 256, 0, stream>>>(xf, WT1cat, pbm1, lb,
                                                       Mb8, 384, EL, pbs1, H1b, 96,
                                                       6, 10, 3);
  conv_agg<96,false><<<AB, 256, 0, stream>>>(off, csr_src, EL, Mb8, H1b, H1b,
                                             batch, psum);
  // ---- layer 2: HID -> HID; units = 6 + 1 = 7, UPB=2 -> y=4 (identity self) ----
  gemm_mfma<96,false><<<dim3(GB16,4), 256, 0, stream>>>(H1b, WT2cat, pbm2, lb+4,
                                                        Mb8, 384, EL, pbm2, nullptr, 0,
                                                        6, 7, 2);
  conv_agg<96,false><<<AB, 256, 0, stream>>>(off, csr_src, EL, Mb8, H1b, H2b,
                                             batch, psum);
  // ---- layer 3: HID -> CC3=64; units = 4 + 1 + 2 = 7, UPB=3 -> y=3; pool fused ----
  gemm_mfma<96,false><<<dim3(GB16,3), 256, 0, stream>>>(H2b, WT3cat, pbm3, lb+8,
                                                        Mb8, 256, EL, pbs3, H3b, 64,
                                                        4, 7, 3);
  conv_agg<64,true><<<AB, 256, 0, stream>>>(off, csr_src, EL, Mb8, H3b, nullptr,
                                            batch, psum);

  // ---- classifier ----
  fc_kernel<<<NG, 64, 0, stream>>>(psum, batch, pWfc, pbfc, (float*)d_out);
}